// Round 1
// baseline (3251.900 us; speedup 1.0000x reference)
//
#include <hip/hip_runtime.h>
#include <float.h>
#include <stddef.h>

#define DIN_   1280
#define DEMB_  512
#define NBAT_  32
#define TA_    128
#define TB_    1024
#define LN_EPS_ 1e-5f

// ---------------- GEMM: C = act(A[M,K] @ W[K,N] + bias) ----------------
// 64x64 tile, KT=32, 256 threads, 4x4 accum per thread.
template<bool RELU>
__global__ __launch_bounds__(256) void gemm_kernel(
    const float* __restrict__ A, const float* __restrict__ W,
    const float* __restrict__ bias, float* __restrict__ C,
    int M, int N, int K)
{
    __shared__ __align__(16) float As[32][68];  // [kk][row], padded stride
    __shared__ __align__(16) float Ws[32][64];  // [kk][col]
    const int t = threadIdx.x;
    const int row0 = blockIdx.x * 64, col0 = blockIdx.y * 64;
    const int ty = t >> 4, tx = t & 15;
    const int r0 = ty * 4, c0 = tx * 4;
    float acc[4][4] = {};
    for (int k0 = 0; k0 < K; k0 += 32) {
        #pragma unroll
        for (int i = 0; i < 2; ++i) {
            int ch = t + i * 256;            // 0..511
            int r = ch >> 3, ko = (ch & 7) * 4;
            float4 v = *(const float4*)(A + (size_t)(row0 + r) * K + k0 + ko);
            As[ko + 0][r] = v.x; As[ko + 1][r] = v.y;
            As[ko + 2][r] = v.z; As[ko + 3][r] = v.w;
        }
        #pragma unroll
        for (int i = 0; i < 2; ++i) {
            int ch = t + i * 256;
            int kk = ch >> 4, c = (ch & 15) * 4;
            *(float4*)&Ws[kk][c] = *(const float4*)(W + (size_t)(k0 + kk) * N + col0 + c);
        }
        __syncthreads();
        #pragma unroll
        for (int kk = 0; kk < 32; ++kk) {
            float4 a4 = *(const float4*)&As[kk][r0];
            float4 b4 = *(const float4*)&Ws[kk][c0];
            float av[4] = {a4.x, a4.y, a4.z, a4.w};
            float bv[4] = {b4.x, b4.y, b4.z, b4.w};
            #pragma unroll
            for (int i = 0; i < 4; ++i)
                #pragma unroll
                for (int j = 0; j < 4; ++j)
                    acc[i][j] = fmaf(av[i], bv[j], acc[i][j]);
        }
        __syncthreads();
    }
    float4 b4 = *(const float4*)(bias + col0 + c0);
    float bv[4] = {b4.x, b4.y, b4.z, b4.w};
    #pragma unroll
    for (int i = 0; i < 4; ++i) {
        float4 o;
        o.x = acc[i][0] + bv[0]; o.y = acc[i][1] + bv[1];
        o.z = acc[i][2] + bv[2]; o.w = acc[i][3] + bv[3];
        if (RELU) {
            o.x = fmaxf(o.x, 0.f); o.y = fmaxf(o.y, 0.f);
            o.z = fmaxf(o.z, 0.f); o.w = fmaxf(o.w, 0.f);
        }
        *(float4*)(C + (size_t)(row0 + r0 + i) * N + col0 + c0) = o;
    }
}

// ---------------- LayerNorm over DEMB=512, one wave per row ----------------
__global__ __launch_bounds__(256) void ln_kernel(
    float* __restrict__ h, const float* __restrict__ g, const float* __restrict__ b)
{
    const int lane = threadIdx.x & 63;
    const int row = blockIdx.x * 4 + (threadIdx.x >> 6);
    float* p = h + (size_t)row * DEMB_;
    float4 v0 = *(const float4*)(p + lane * 4);
    float4 v1 = *(const float4*)(p + 256 + lane * 4);
    float x[8] = {v0.x, v0.y, v0.z, v0.w, v1.x, v1.y, v1.z, v1.w};
    float s = 0.f;
    #pragma unroll
    for (int i = 0; i < 8; ++i) s += x[i];
    #pragma unroll
    for (int d = 32; d >= 1; d >>= 1) s += __shfl_xor(s, d);
    float mu = s * (1.f / DEMB_);
    float sq = 0.f;
    #pragma unroll
    for (int i = 0; i < 8; ++i) { float dd = x[i] - mu; sq += dd * dd; }
    #pragma unroll
    for (int d = 32; d >= 1; d >>= 1) sq += __shfl_xor(sq, d);
    float var = sq * (1.f / DEMB_);
    float rs = 1.f / sqrtf(var + LN_EPS_);
    float4 g0 = *(const float4*)(g + lane * 4);
    float4 g1 = *(const float4*)(g + 256 + lane * 4);
    float4 b0 = *(const float4*)(b + lane * 4);
    float4 b1 = *(const float4*)(b + 256 + lane * 4);
    float gg[8] = {g0.x, g0.y, g0.z, g0.w, g1.x, g1.y, g1.z, g1.w};
    float bb[8] = {b0.x, b0.y, b0.z, b0.w, b1.x, b1.y, b1.z, b1.w};
    float y[8];
    #pragma unroll
    for (int i = 0; i < 8; ++i) y[i] = (x[i] - mu) * rs * gg[i] + bb[i];
    *(float4*)(p + lane * 4)       = make_float4(y[0], y[1], y[2], y[3]);
    *(float4*)(p + 256 + lane * 4) = make_float4(y[4], y[5], y[6], y[7]);
}

// ---------------- L2 normalize rows ----------------
__global__ __launch_bounds__(256) void l2norm_kernel(float* __restrict__ h)
{
    const int lane = threadIdx.x & 63;
    const int row = blockIdx.x * 4 + (threadIdx.x >> 6);
    float* p = h + (size_t)row * DEMB_;
    float4 v0 = *(const float4*)(p + lane * 4);
    float4 v1 = *(const float4*)(p + 256 + lane * 4);
    float sq = v0.x*v0.x + v0.y*v0.y + v0.z*v0.z + v0.w*v0.w
             + v1.x*v1.x + v1.y*v1.y + v1.z*v1.z + v1.w*v1.w;
    #pragma unroll
    for (int d = 32; d >= 1; d >>= 1) sq += __shfl_xor(sq, d);
    float rs = 1.f / sqrtf(sq);
    v0.x *= rs; v0.y *= rs; v0.z *= rs; v0.w *= rs;
    v1.x *= rs; v1.y *= rs; v1.z *= rs; v1.w *= rs;
    *(float4*)(p + lane * 4) = v0;
    *(float4*)(p + 256 + lane * 4) = v1;
}

// ---------------- Fused sim + masked max + masked mean ----------------
// One block per (a,b) pair. S-tile 128x32, K-loop over 512.
__global__ __launch_bounds__(256) void sim_kernel(
    const float* __restrict__ hA,   // [32,128,512]
    const float* __restrict__ hB,   // [32,1024,512]
    const int*  __restrict__ mA,    // [32,128]
    const int*  __restrict__ mB,    // [32,1024]
    const float* __restrict__ temp, // [1]
    float* __restrict__ out)        // [2,32,32]
{
    __shared__ __align__(16) float As[32][132];   // [kk][t-row]
    __shared__ __align__(16) float Bs[32][36];    // [kk][s-col]
    __shared__ float sAmax[TA_];
    __shared__ float colbuf[32][33];
    __shared__ int   mAl[TA_];
    __shared__ int   mBl[32];
    __shared__ float redN[4], redC[4];

    const int a = blockIdx.x >> 5;
    const int b = blockIdx.x & 31;
    const int t = threadIdx.x;
    const int ty = t >> 3, tx = t & 7;     // 32 x 8
    const int r0 = ty * 4, c0 = tx * 4;
    const float invT = 1.0f / temp[0];
    const float* Abase = hA + (size_t)a * TA_ * DEMB_;
    const float* Bbase = hB + (size_t)b * TB_ * DEMB_;

    if (t < TA_) { sAmax[t] = -FLT_MAX; mAl[t] = mA[a * TA_ + t]; }
    float sumB = 0.f, cntB = 0.f;          // live in threads t<32 only

    __syncthreads();

    for (int s0 = 0; s0 < TB_; s0 += 32) {
        if (t < 32) mBl[t] = mB[b * TB_ + s0 + t];
        float acc[4][4] = {};
        for (int k0 = 0; k0 < DEMB_; k0 += 32) {
            // A chunk: 128 rows x 32 k
            {
                int tr = t >> 1;
                int ko = (t & 1) * 16;
                const float* src = Abase + (size_t)tr * DEMB_ + k0 + ko;
                #pragma unroll
                for (int j = 0; j < 4; ++j) {
                    float4 v = *(const float4*)(src + j * 4);
                    int kk = ko + j * 4;
                    As[kk + 0][tr] = v.x; As[kk + 1][tr] = v.y;
                    As[kk + 2][tr] = v.z; As[kk + 3][tr] = v.w;
                }
            }
            // B chunk: 32 rows x 32 k
            {
                int s = t >> 3;
                int ko = (t & 7) * 4;
                float4 v = *(const float4*)(Bbase + (size_t)(s0 + s) * DEMB_ + k0 + ko);
                Bs[ko + 0][s] = v.x; Bs[ko + 1][s] = v.y;
                Bs[ko + 2][s] = v.z; Bs[ko + 3][s] = v.w;
            }
            __syncthreads();
            #pragma unroll
            for (int kk = 0; kk < 32; ++kk) {
                float4 a4 = *(const float4*)&As[kk][r0];
                float4 b4 = *(const float4*)&Bs[kk][c0];
                float av[4] = {a4.x, a4.y, a4.z, a4.w};
                float bv[4] = {b4.x, b4.y, b4.z, b4.w};
                #pragma unroll
                for (int i = 0; i < 4; ++i)
                    #pragma unroll
                    for (int j = 0; j < 4; ++j)
                        acc[i][j] = fmaf(av[i], bv[j], acc[i][j]);
            }
            __syncthreads();
        }
        // mask + temperature, row/col maxes
        float rmax[4] = {-FLT_MAX, -FLT_MAX, -FLT_MAX, -FLT_MAX};
        float cmax[4] = {-FLT_MAX, -FLT_MAX, -FLT_MAX, -FLT_MAX};
        #pragma unroll
        for (int i = 0; i < 4; ++i) {
            bool okr = mAl[r0 + i] != 0;
            #pragma unroll
            for (int j = 0; j < 4; ++j) {
                float v = acc[i][j] * invT;
                bool ok = okr && (mBl[c0 + j] != 0);
                float mv = ok ? v : -FLT_MAX;
                rmax[i] = fmaxf(rmax[i], mv);
                cmax[j] = fmaxf(cmax[j], mv);
            }
        }
        // row max across the 8 threads sharing a row group (lanes xor 1,2,4)
        #pragma unroll
        for (int d = 1; d < 8; d <<= 1) {
            #pragma unroll
            for (int i = 0; i < 4; ++i)
                rmax[i] = fmaxf(rmax[i], __shfl_xor(rmax[i], d));
        }
        if (tx == 0) {
            #pragma unroll
            for (int i = 0; i < 4; ++i)
                sAmax[r0 + i] = fmaxf(sAmax[r0 + i], rmax[i]);
        }
        // col max: stage per-ty partials then reduce
        #pragma unroll
        for (int j = 0; j < 4; ++j) colbuf[ty][c0 + j] = cmax[j];
        __syncthreads();
        if (t < 32) {
            float m = -FLT_MAX;
            #pragma unroll 8
            for (int y = 0; y < 32; ++y) m = fmaxf(m, colbuf[y][t]);
            if (mBl[t] != 0) { sumB += m; cntB += 1.f; }
        }
        __syncthreads();
    }

    // masked mean over tA
    float numA = 0.f, cA = 0.f;
    if (t < TA_ && mAl[t] != 0) { numA = sAmax[t]; cA = 1.f; }
    #pragma unroll
    for (int d = 32; d >= 1; d >>= 1) {
        numA += __shfl_xor(numA, d);
        cA   += __shfl_xor(cA, d);
    }
    if ((t & 63) == 0) { redN[t >> 6] = numA; redC[t >> 6] = cA; }
    __syncthreads();
    if (t == 0) {
        float n = redN[0] + redN[1] + redN[2] + redN[3];
        float c = redC[0] + redC[1] + redC[2] + redC[3];
        out[a * NBAT_ + b] = n / fmaxf(c, 1e-6f);
    }
    // masked mean over tB (partials live in wave 0, threads 0..31)
    float nB = sumB, cB = cntB;
    #pragma unroll
    for (int d = 32; d >= 1; d >>= 1) {
        nB += __shfl_xor(nB, d);
        cB += __shfl_xor(cB, d);
    }
    if (t == 0) out[NBAT_ * NBAT_ + a * NBAT_ + b] = nB / fmaxf(cB, 1e-6f);
}

// ---------------- launch ----------------
extern "C" void kernel_launch(void* const* d_in, const int* in_sizes, int n_in,
                              void* d_out, int out_size, void* d_ws, size_t ws_size,
                              hipStream_t stream)
{
    const float* pep_esm  = (const float*)d_in[0];
    const float* rec_esm  = (const float*)d_in[1];
    const int*   pep_mask = (const int*)d_in[2];
    const int*   rec_mask = (const int*)d_in[3];
    const float* temp     = (const float*)d_in[4];
    const float* pep_pw  = (const float*)d_in[5];
    const float* pep_pb  = (const float*)d_in[6];
    const float* pep_f1w = (const float*)d_in[7];
    const float* pep_f1b = (const float*)d_in[8];
    const float* pep_lng = (const float*)d_in[9];
    const float* pep_lnb = (const float*)d_in[10];
    const float* pep_f2w = (const float*)d_in[11];
    const float* pep_f2b = (const float*)d_in[12];
    const float* rec_pw  = (const float*)d_in[13];
    const float* rec_pb  = (const float*)d_in[14];
    const float* rec_f1w = (const float*)d_in[15];
    const float* rec_f1b = (const float*)d_in[16];
    const float* rec_lng = (const float*)d_in[17];
    const float* rec_lnb = (const float*)d_in[18];
    const float* rec_f2w = (const float*)d_in[19];
    const float* rec_f2b = (const float*)d_in[20];
    float* out = (float*)d_out;

    const int Mr = NBAT_ * TB_;   // 32768
    const int Mp = NBAT_ * TA_;   // 4096
    float* buf1 = (float*)d_ws;                       // 32768*512 f32
    float* buf2 = buf1 + (size_t)Mr * DEMB_;          // 32768*512 f32
    float* pA = buf2;                                 // pep scratch (after rec h dead)
    float* pB = buf2 + (size_t)Mp * DEMB_;

    dim3 blk(256);
    // --- rec encoder ---
    gemm_kernel<false><<<dim3(Mr / 64, DEMB_ / 64), blk, 0, stream>>>(rec_esm, rec_pw, rec_pb, buf1, Mr, DEMB_, DIN_);
    gemm_kernel<true ><<<dim3(Mr / 64, DEMB_ / 64), blk, 0, stream>>>(buf1, rec_f1w, rec_f1b, buf2, Mr, DEMB_, DEMB_);
    ln_kernel<<<dim3(Mr / 4), blk, 0, stream>>>(buf2, rec_lng, rec_lnb);
    gemm_kernel<false><<<dim3(Mr / 64, DEMB_ / 64), blk, 0, stream>>>(buf2, rec_f2w, rec_f2b, buf1, Mr, DEMB_, DEMB_);
    l2norm_kernel<<<dim3(Mr / 4), blk, 0, stream>>>(buf1);
    // --- pep encoder ---
    gemm_kernel<false><<<dim3(Mp / 64, DEMB_ / 64), blk, 0, stream>>>(pep_esm, pep_pw, pep_pb, pA, Mp, DEMB_, DIN_);
    gemm_kernel<true ><<<dim3(Mp / 64, DEMB_ / 64), blk, 0, stream>>>(pA, pep_f1w, pep_f1b, pB, Mp, DEMB_, DEMB_);
    ln_kernel<<<dim3(Mp / 4), blk, 0, stream>>>(pB, pep_lng, pep_lnb);
    gemm_kernel<false><<<dim3(Mp / 64, DEMB_ / 64), blk, 0, stream>>>(pB, pep_f2w, pep_f2b, pA, Mp, DEMB_, DEMB_);
    l2norm_kernel<<<dim3(Mp / 4), blk, 0, stream>>>(pA);
    // --- fused similarity ---
    sim_kernel<<<dim3(NBAT_ * NBAT_), blk, 0, stream>>>(pA, buf1, pep_mask, rec_mask, temp, out);
}

// Round 2
// 1404.973 us; speedup vs baseline: 2.3146x; 2.3146x over previous
//
#include <hip/hip_runtime.h>
#include <float.h>
#include <stddef.h>
#include <stdint.h>

#define DIN_   1280
#define DEMB_  512
#define NBAT_  32
#define TA_    128
#define TB_    1024
#define LN_EPS_ 1e-5f

using short8 = __attribute__((ext_vector_type(8))) short;
using f32x4  = __attribute__((ext_vector_type(4))) float;

typedef const __attribute__((address_space(1))) unsigned int gu32;
typedef __attribute__((address_space(3))) unsigned int lu32;

__device__ __forceinline__ void gld_lds16(const void* g, void* l) {
    __builtin_amdgcn_global_load_lds((gu32*)g, (lu32*)l, 16, 0, 0);
}

__device__ __forceinline__ unsigned short f2bf(float x) {
    unsigned u = __float_as_uint(x);
    u += 0x7FFFu + ((u >> 16) & 1u);
    return (unsigned short)(u >> 16);
}

// ---------------- GEMM: C = act(A[M,K] @ W[K,N] + bias) (fp32, encoders) ----------------
template<bool RELU>
__global__ __launch_bounds__(256) void gemm_kernel(
    const float* __restrict__ A, const float* __restrict__ W,
    const float* __restrict__ bias, float* __restrict__ C,
    int M, int N, int K)
{
    __shared__ __align__(16) float As[32][68];
    __shared__ __align__(16) float Ws[32][64];
    const int t = threadIdx.x;
    const int row0 = blockIdx.x * 64, col0 = blockIdx.y * 64;
    const int ty = t >> 4, tx = t & 15;
    const int r0 = ty * 4, c0 = tx * 4;
    float acc[4][4] = {};
    for (int k0 = 0; k0 < K; k0 += 32) {
        #pragma unroll
        for (int i = 0; i < 2; ++i) {
            int ch = t + i * 256;
            int r = ch >> 3, ko = (ch & 7) * 4;
            float4 v = *(const float4*)(A + (size_t)(row0 + r) * K + k0 + ko);
            As[ko + 0][r] = v.x; As[ko + 1][r] = v.y;
            As[ko + 2][r] = v.z; As[ko + 3][r] = v.w;
        }
        #pragma unroll
        for (int i = 0; i < 2; ++i) {
            int ch = t + i * 256;
            int kk = ch >> 4, c = (ch & 15) * 4;
            *(float4*)&Ws[kk][c] = *(const float4*)(W + (size_t)(k0 + kk) * N + col0 + c);
        }
        __syncthreads();
        #pragma unroll
        for (int kk = 0; kk < 32; ++kk) {
            float4 a4 = *(const float4*)&As[kk][r0];
            float4 b4 = *(const float4*)&Ws[kk][c0];
            float av[4] = {a4.x, a4.y, a4.z, a4.w};
            float bv[4] = {b4.x, b4.y, b4.z, b4.w};
            #pragma unroll
            for (int i = 0; i < 4; ++i)
                #pragma unroll
                for (int j = 0; j < 4; ++j)
                    acc[i][j] = fmaf(av[i], bv[j], acc[i][j]);
        }
        __syncthreads();
    }
    float4 b4 = *(const float4*)(bias + col0 + c0);
    float bv[4] = {b4.x, b4.y, b4.z, b4.w};
    #pragma unroll
    for (int i = 0; i < 4; ++i) {
        float4 o;
        o.x = acc[i][0] + bv[0]; o.y = acc[i][1] + bv[1];
        o.z = acc[i][2] + bv[2]; o.w = acc[i][3] + bv[3];
        if (RELU) {
            o.x = fmaxf(o.x, 0.f); o.y = fmaxf(o.y, 0.f);
            o.z = fmaxf(o.z, 0.f); o.w = fmaxf(o.w, 0.f);
        }
        *(float4*)(C + (size_t)(row0 + r0 + i) * N + col0 + c0) = o;
    }
}

// ---------------- LayerNorm over DEMB=512, one wave per row ----------------
__global__ __launch_bounds__(256) void ln_kernel(
    float* __restrict__ h, const float* __restrict__ g, const float* __restrict__ b)
{
    const int lane = threadIdx.x & 63;
    const int row = blockIdx.x * 4 + (threadIdx.x >> 6);
    float* p = h + (size_t)row * DEMB_;
    float4 v0 = *(const float4*)(p + lane * 4);
    float4 v1 = *(const float4*)(p + 256 + lane * 4);
    float x[8] = {v0.x, v0.y, v0.z, v0.w, v1.x, v1.y, v1.z, v1.w};
    float s = 0.f;
    #pragma unroll
    for (int i = 0; i < 8; ++i) s += x[i];
    #pragma unroll
    for (int d = 32; d >= 1; d >>= 1) s += __shfl_xor(s, d);
    float mu = s * (1.f / DEMB_);
    float sq = 0.f;
    #pragma unroll
    for (int i = 0; i < 8; ++i) { float dd = x[i] - mu; sq += dd * dd; }
    #pragma unroll
    for (int d = 32; d >= 1; d >>= 1) sq += __shfl_xor(sq, d);
    float var = sq * (1.f / DEMB_);
    float rs = 1.f / sqrtf(var + LN_EPS_);
    float4 g0 = *(const float4*)(g + lane * 4);
    float4 g1 = *(const float4*)(g + 256 + lane * 4);
    float4 b0 = *(const float4*)(b + lane * 4);
    float4 b1 = *(const float4*)(b + 256 + lane * 4);
    float gg[8] = {g0.x, g0.y, g0.z, g0.w, g1.x, g1.y, g1.z, g1.w};
    float bb[8] = {b0.x, b0.y, b0.z, b0.w, b1.x, b1.y, b1.z, b1.w};
    float y[8];
    #pragma unroll
    for (int i = 0; i < 8; ++i) y[i] = (x[i] - mu) * rs * gg[i] + bb[i];
    *(float4*)(p + lane * 4)       = make_float4(y[0], y[1], y[2], y[3]);
    *(float4*)(p + 256 + lane * 4) = make_float4(y[4], y[5], y[6], y[7]);
}

// ---------------- L2 normalize rows -> bf16 output ----------------
__global__ __launch_bounds__(256) void l2norm_bf16_kernel(
    const float* __restrict__ h, unsigned short* __restrict__ o)
{
    const int lane = threadIdx.x & 63;
    const int row = blockIdx.x * 4 + (threadIdx.x >> 6);
    const float* p = h + (size_t)row * DEMB_;
    float4 v0 = *(const float4*)(p + lane * 4);
    float4 v1 = *(const float4*)(p + 256 + lane * 4);
    float sq = v0.x*v0.x + v0.y*v0.y + v0.z*v0.z + v0.w*v0.w
             + v1.x*v1.x + v1.y*v1.y + v1.z*v1.z + v1.w*v1.w;
    #pragma unroll
    for (int d = 32; d >= 1; d >>= 1) sq += __shfl_xor(sq, d);
    float rs = 1.f / sqrtf(sq);
    ushort4 o0, o1;
    o0.x = f2bf(v0.x * rs); o0.y = f2bf(v0.y * rs);
    o0.z = f2bf(v0.z * rs); o0.w = f2bf(v0.w * rs);
    o1.x = f2bf(v1.x * rs); o1.y = f2bf(v1.y * rs);
    o1.z = f2bf(v1.z * rs); o1.w = f2bf(v1.w * rs);
    *(ushort4*)(o + (size_t)row * DEMB_ + lane * 4)       = o0;
    *(ushort4*)(o + (size_t)row * DEMB_ + 256 + lane * 4) = o1;
}

// ---------------- Fused sim (bf16 MFMA) + masked max + masked mean ----------------
// 1 block per (a,b); 512 thr = 8 waves (2 M x 4 N); tile 128x128, BK=64.
__global__ __launch_bounds__(512, 4) void sim_mfma_kernel(
    const unsigned short* __restrict__ hA,  // bf16 [32*128, 512]
    const unsigned short* __restrict__ hB,  // bf16 [32*1024, 512]
    const int* __restrict__ mA, const int* __restrict__ mB,
    const float* __restrict__ temp, float* __restrict__ out)
{
    __shared__ __align__(16) unsigned char Abuf[128 * 64 * 2];
    __shared__ __align__(16) unsigned char Bbuf[128 * 64 * 2];
    __shared__ float rowpart[4][128];
    __shared__ float colpart[2][128];
    __shared__ float red[2][4];

    // XCD-aware swizzle: XCD x (bid%8) handles b in [4x, 4x+4) -> 4MB hB slice per L2
    const int bid = blockIdx.x;
    const int g = (bid & 7) * 128 + (bid >> 3);
    const int b = g >> 5, a = g & 31;

    const int t = threadIdx.x;
    const int wave = t >> 6, lane = t & 63;
    const int wr = wave >> 2, wc = wave & 3;
    const int cl = lane & 15, rg = lane >> 4;
    const float invT = 1.0f / temp[0];

    // staging: chunk p (16B) -> LDS linear p*16; holds logical (row=p>>3, c16=(p&7)^(row&7))
    const int pr0 = t >> 3,        pq0 = t & 7;
    const int pr1 = pr0 + 64;
    const int ks0 = ((pq0 ^ (pr0 & 7)) * 8);
    const int ks1 = ((pq0 ^ (pr1 & 7)) * 8);
    const unsigned short* Aglob = hA + (size_t)(a * TA_) * DEMB_;
    const unsigned short* Bglob = hB + (size_t)(b * TB_) * DEMB_;

    // per-thread row-mask bits (16 rows this thread owns in C)
    unsigned mabits = 0;
    #pragma unroll
    for (int m = 0; m < 4; ++m)
        #pragma unroll
        for (int j = 0; j < 4; ++j) {
            int r = wr * 64 + m * 16 + rg * 4 + j;
            if (mA[a * TA_ + r]) mabits |= 1u << (m * 4 + j);
        }

    // fragment LDS addresses (swizzled read): addr = row*128 + (cb ^ ((row&7)<<4))
    int aoff[4], asw[4], boff[2], bsw[2];
    #pragma unroll
    for (int m = 0; m < 4; ++m) {
        int r = wr * 64 + m * 16 + cl;
        aoff[m] = r * 128; asw[m] = (r & 7) << 4;
    }
    #pragma unroll
    for (int n = 0; n < 2; ++n) {
        int c = wc * 32 + n * 16 + cl;
        boff[n] = c * 128; bsw[n] = (c & 7) << 4;
    }

    float rowrun = -FLT_MAX, sumB = 0.f, cntB = 0.f;

    for (int s0 = 0; s0 < TB_; s0 += 128) {
        const int mb0 = mB[b * TB_ + s0 + wc * 32 + cl];
        const int mb1 = mB[b * TB_ + s0 + wc * 32 + 16 + cl];
        f32x4 acc[4][2];
        #pragma unroll
        for (int m = 0; m < 4; ++m) {
            acc[m][0] = (f32x4){0.f, 0.f, 0.f, 0.f};
            acc[m][1] = (f32x4){0.f, 0.f, 0.f, 0.f};
        }
        for (int k0 = 0; k0 < DEMB_; k0 += 64) {
            gld_lds16(Aglob + (size_t)pr0 * DEMB_ + k0 + ks0, Abuf + t * 16);
            gld_lds16(Aglob + (size_t)pr1 * DEMB_ + k0 + ks1, Abuf + (t + 512) * 16);
            gld_lds16(Bglob + (size_t)(s0 + pr0) * DEMB_ + k0 + ks0, Bbuf + t * 16);
            gld_lds16(Bglob + (size_t)(s0 + pr1) * DEMB_ + k0 + ks1, Bbuf + (t + 512) * 16);
            __syncthreads();
            #pragma unroll
            for (int h = 0; h < 2; ++h) {
                const int cb = h * 64 + rg * 16;
                short8 av[4], bv[2];
                #pragma unroll
                for (int m = 0; m < 4; ++m)
                    av[m] = *(const short8*)(Abuf + aoff[m] + (cb ^ asw[m]));
                #pragma unroll
                for (int n = 0; n < 2; ++n)
                    bv[n] = *(const short8*)(Bbuf + boff[n] + (cb ^ bsw[n]));
                #pragma unroll
                for (int m = 0; m < 4; ++m)
                    #pragma unroll
                    for (int n = 0; n < 2; ++n)
                        acc[m][n] = __builtin_amdgcn_mfma_f32_16x16x32_bf16(
                            av[m], bv[n], acc[m][n], 0, 0, 0);
            }
            __syncthreads();
        }
        // ---- epilogue: mask + scale, row/col maxes ----
        float rmax[4][4];
        float cmax0 = -FLT_MAX, cmax1 = -FLT_MAX;
        #pragma unroll
        for (int m = 0; m < 4; ++m) {
            #pragma unroll
            for (int j = 0; j < 4; ++j) {
                const bool ra = (mabits >> (m * 4 + j)) & 1;
                float v0 = (ra && mb0) ? acc[m][0][j] * invT : -FLT_MAX;
                float v1 = (ra && mb1) ? acc[m][1][j] * invT : -FLT_MAX;
                rmax[m][j] = fmaxf(v0, v1);
                cmax0 = fmaxf(cmax0, v0);
                cmax1 = fmaxf(cmax1, v1);
            }
        }
        #pragma unroll
        for (int d = 1; d < 16; d <<= 1)
            #pragma unroll
            for (int m = 0; m < 4; ++m)
                #pragma unroll
                for (int j = 0; j < 4; ++j)
                    rmax[m][j] = fmaxf(rmax[m][j], __shfl_xor(rmax[m][j], d));
        cmax0 = fmaxf(cmax0, __shfl_xor(cmax0, 16));
        cmax0 = fmaxf(cmax0, __shfl_xor(cmax0, 32));
        cmax1 = fmaxf(cmax1, __shfl_xor(cmax1, 16));
        cmax1 = fmaxf(cmax1, __shfl_xor(cmax1, 32));
        if (cl == 0) {
            #pragma unroll
            for (int m = 0; m < 4; ++m)
                #pragma unroll
                for (int j = 0; j < 4; ++j)
                    rowpart[wc][wr * 64 + m * 16 + rg * 4 + j] = rmax[m][j];
        }
        if (rg == 0) {
            colpart[wr][wc * 32 + cl]      = cmax0;
            colpart[wr][wc * 32 + 16 + cl] = cmax1;
        }
        __syncthreads();
        if (t < 128) {
            float r = fmaxf(fmaxf(rowpart[0][t], rowpart[1][t]),
                            fmaxf(rowpart[2][t], rowpart[3][t]));
            rowrun = fmaxf(rowrun, r);
            float cm = fmaxf(colpart[0][t], colpart[1][t]);
            if (mB[b * TB_ + s0 + t]) { sumB += cm; cntB += 1.f; }
        }
        __syncthreads();
    }

    // ---- final masked means ----
    float numA = 0.f, cA = 0.f;
    if (t < 128 && mA[a * TA_ + t]) { numA = rowrun; cA = 1.f; }
    #pragma unroll
    for (int d = 32; d >= 1; d >>= 1) {
        numA += __shfl_xor(numA, d);
        cA   += __shfl_xor(cA, d);
        sumB += __shfl_xor(sumB, d);
        cntB += __shfl_xor(cntB, d);
    }
    if (wave < 2 && lane == 0) {
        red[wave][0] = numA; red[wave][1] = cA;
        red[wave][2] = sumB; red[wave][3] = cntB;
    }
    __syncthreads();
    if (t == 0) {
        float n  = red[0][0] + red[1][0];
        float c  = red[0][1] + red[1][1];
        float nb = red[0][2] + red[1][2];
        float cb = red[0][3] + red[1][3];
        out[a * NBAT_ + b] = n / fmaxf(c, 1e-6f);
        out[NBAT_ * NBAT_ + a * NBAT_ + b] = nb / fmaxf(cb, 1e-6f);
    }
}

// ---------------- launch ----------------
extern "C" void kernel_launch(void* const* d_in, const int* in_sizes, int n_in,
                              void* d_out, int out_size, void* d_ws, size_t ws_size,
                              hipStream_t stream)
{
    const float* pep_esm  = (const float*)d_in[0];
    const float* rec_esm  = (const float*)d_in[1];
    const int*   pep_mask = (const int*)d_in[2];
    const int*   rec_mask = (const int*)d_in[3];
    const float* temp     = (const float*)d_in[4];
    const float* pep_pw  = (const float*)d_in[5];
    const float* pep_pb  = (const float*)d_in[6];
    const float* pep_f1w = (const float*)d_in[7];
    const float* pep_f1b = (const float*)d_in[8];
    const float* pep_lng = (const float*)d_in[9];
    const float* pep_lnb = (const float*)d_in[10];
    const float* pep_f2w = (const float*)d_in[11];
    const float* pep_f2b = (const float*)d_in[12];
    const float* rec_pw  = (const float*)d_in[13];
    const float* rec_pb  = (const float*)d_in[14];
    const float* rec_f1w = (const float*)d_in[15];
    const float* rec_f1b = (const float*)d_in[16];
    const float* rec_lng = (const float*)d_in[17];
    const float* rec_lnb = (const float*)d_in[18];
    const float* rec_f2w = (const float*)d_in[19];
    const float* rec_f2b = (const float*)d_in[20];
    float* out = (float*)d_out;

    const int Mr = NBAT_ * TB_;   // 32768
    const int Mp = NBAT_ * TA_;   // 4096
    float* buf1 = (float*)d_ws;                       // 64MB fp32
    float* buf2 = buf1 + (size_t)Mr * DEMB_;          // 64MB region
    unsigned short* hB_bf = (unsigned short*)buf2;                          // 32MB
    float* pA = (float*)((char*)buf2 + (size_t)32 * 1024 * 1024);           // 8MB
    float* pB = pA + (size_t)Mp * DEMB_;                                    // 8MB
    unsigned short* hA_bf = (unsigned short*)(pB + (size_t)Mp * DEMB_);     // 4MB

    dim3 blk(256);
    // --- rec encoder (fp32) ---
    gemm_kernel<false><<<dim3(Mr / 64, DEMB_ / 64), blk, 0, stream>>>(rec_esm, rec_pw, rec_pb, buf1, Mr, DEMB_, DIN_);
    gemm_kernel<true ><<<dim3(Mr / 64, DEMB_ / 64), blk, 0, stream>>>(buf1, rec_f1w, rec_f1b, buf2, Mr, DEMB_, DEMB_);
    ln_kernel<<<dim3(Mr / 4), blk, 0, stream>>>(buf2, rec_lng, rec_lnb);
    gemm_kernel<false><<<dim3(Mr / 64, DEMB_ / 64), blk, 0, stream>>>(buf2, rec_f2w, rec_f2b, buf1, Mr, DEMB_, DEMB_);
    l2norm_bf16_kernel<<<dim3(Mr / 4), blk, 0, stream>>>(buf1, hB_bf);
    // --- pep encoder (fp32) ---
    gemm_kernel<false><<<dim3(Mp / 64, DEMB_ / 64), blk, 0, stream>>>(pep_esm, pep_pw, pep_pb, pA, Mp, DEMB_, DIN_);
    gemm_kernel<true ><<<dim3(Mp / 64, DEMB_ / 64), blk, 0, stream>>>(pA, pep_f1w, pep_f1b, pB, Mp, DEMB_, DEMB_);
    ln_kernel<<<dim3(Mp / 4), blk, 0, stream>>>(pB, pep_lng, pep_lnb);
    gemm_kernel<false><<<dim3(Mp / 64, DEMB_ / 64), blk, 0, stream>>>(pB, pep_f2w, pep_f2b, pA, Mp, DEMB_, DEMB_);
    l2norm_bf16_kernel<<<dim3(Mp / 4), blk, 0, stream>>>(pA, hA_bf);
    // --- fused similarity (bf16 MFMA) ---
    sim_mfma_kernel<<<dim3(NBAT_ * NBAT_), dim3(512), 0, stream>>>(hA_bf, hB_bf, pep_mask, rec_mask, temp, out);
}

// Round 4
// 465.944 us; speedup vs baseline: 6.9792x; 3.0153x over previous
//
#include <hip/hip_runtime.h>
#include <float.h>
#include <stddef.h>
#include <stdint.h>

#define DIN_   1280
#define DEMB_  512
#define NBAT_  32
#define TA_    128
#define TB_    1024
#define LN_EPS_ 1e-5f

using short8  = __attribute__((ext_vector_type(8))) short;
using ushort8 = __attribute__((ext_vector_type(8))) unsigned short;
using f32x4   = __attribute__((ext_vector_type(4))) float;

typedef const __attribute__((address_space(1))) unsigned int gu32;
typedef __attribute__((address_space(3))) unsigned int lu32;

__device__ __forceinline__ void gld_lds16(const void* g, void* l) {
    __builtin_amdgcn_global_load_lds((gu32*)g, (lu32*)l, 16, 0, 0);
}

__device__ __forceinline__ unsigned short f2bf(float x) {
    unsigned u = __float_as_uint(x);
    u += 0x7FFFu + ((u >> 16) & 1u);
    return (unsigned short)(u >> 16);
}
__device__ __forceinline__ float bf2f(unsigned short u) {
    return __uint_as_float((unsigned)u << 16);
}

// ---------------- weight transpose+convert: Wt[n,k] = bf16(W[k,n]) ----------------
__global__ __launch_bounds__(256) void wtrans_kernel(
    const float* __restrict__ W, unsigned short* __restrict__ Wt, int K, int N)
{
    __shared__ float tile[32][33];
    const int k0 = blockIdx.x * 32, n0 = blockIdx.y * 32;
    const int r = threadIdx.x >> 5, c = threadIdx.x & 31;
    #pragma unroll
    for (int i = 0; i < 4; ++i)
        tile[r + i * 8][c] = W[(size_t)(k0 + r + i * 8) * N + n0 + c];
    __syncthreads();
    #pragma unroll
    for (int i = 0; i < 4; ++i)
        Wt[(size_t)(n0 + r + i * 8) * K + k0 + c] = f2bf(tile[c][r + i * 8]);
}

// ---------------- encoder GEMM, A=bf16 [M,K], Wt=bf16 [512,K], C=bf16 [M,512] ----------------
// 128x128 tile, BK=64, 512 thr = 8 waves (2Mx4N). blockIdx.x = rt*4 + ct (col fastest).
template<int K, bool RELU>
__global__ __launch_bounds__(512, 4) void egemm_bf16(
    const unsigned short* __restrict__ A, const unsigned short* __restrict__ Wt,
    const float* __restrict__ bias, unsigned short* __restrict__ C)
{
    __shared__ __align__(16) unsigned char Abuf[128 * 64 * 2];
    __shared__ __align__(16) unsigned char Bbuf[128 * 64 * 2];
    const int bid = blockIdx.x;
    const int row0 = (bid >> 2) * 128, col0 = (bid & 3) * 128;
    const int t = threadIdx.x;
    const int wave = t >> 6, lane = t & 63;
    const int wr = wave >> 2, wc = wave & 3;
    const int cl = lane & 15, rg = lane >> 4;

    const int pr0 = t >> 3, pq0 = t & 7;
    const int pr1 = pr0 + 64;
    const int ks0 = ((pq0 ^ (pr0 & 7)) * 8);
    const int ks1 = ((pq0 ^ (pr1 & 7)) * 8);
    const unsigned short* Aglob = A + (size_t)row0 * K;
    const unsigned short* Bglob = Wt + (size_t)col0 * K;

    int aoff[4], asw[4], boff[2], bsw[2];
    #pragma unroll
    for (int m = 0; m < 4; ++m) {
        int r = wr * 64 + m * 16 + cl;
        aoff[m] = r * 128; asw[m] = (r & 7) << 4;
    }
    #pragma unroll
    for (int n = 0; n < 2; ++n) {
        int c = wc * 32 + n * 16 + cl;
        boff[n] = c * 128; bsw[n] = (c & 7) << 4;
    }

    f32x4 acc[4][2];
    #pragma unroll
    for (int m = 0; m < 4; ++m) {
        acc[m][0] = (f32x4){0.f, 0.f, 0.f, 0.f};
        acc[m][1] = (f32x4){0.f, 0.f, 0.f, 0.f};
    }
    for (int k0 = 0; k0 < K; k0 += 64) {
        gld_lds16(Aglob + (size_t)pr0 * K + k0 + ks0, Abuf + t * 16);
        gld_lds16(Aglob + (size_t)pr1 * K + k0 + ks1, Abuf + (t + 512) * 16);
        gld_lds16(Bglob + (size_t)pr0 * K + k0 + ks0, Bbuf + t * 16);
        gld_lds16(Bglob + (size_t)pr1 * K + k0 + ks1, Bbuf + (t + 512) * 16);
        __syncthreads();
        #pragma unroll
        for (int h = 0; h < 2; ++h) {
            const int cb = h * 64 + rg * 16;
            short8 av[4], bv[2];
            #pragma unroll
            for (int m = 0; m < 4; ++m)
                av[m] = *(const short8*)(Abuf + aoff[m] + (cb ^ asw[m]));
            #pragma unroll
            for (int n = 0; n < 2; ++n)
                bv[n] = *(const short8*)(Bbuf + boff[n] + (cb ^ bsw[n]));
            #pragma unroll
            for (int m = 0; m < 4; ++m)
                #pragma unroll
                for (int n = 0; n < 2; ++n)
                    acc[m][n] = __builtin_amdgcn_mfma_f32_16x16x32_bf16(
                        av[m], bv[n], acc[m][n], 0, 0, 0);
        }
        __syncthreads();
    }
    const float b0 = bias[col0 + wc * 32 + cl];
    const float b1 = bias[col0 + wc * 32 + 16 + cl];
    #pragma unroll
    for (int m = 0; m < 4; ++m)
        #pragma unroll
        for (int j = 0; j < 4; ++j) {
            int row = row0 + wr * 64 + m * 16 + rg * 4 + j;
            float v0 = acc[m][0][j] + b0;
            float v1 = acc[m][1][j] + b1;
            if (RELU) { v0 = fmaxf(v0, 0.f); v1 = fmaxf(v1, 0.f); }
            C[(size_t)row * DEMB_ + col0 + wc * 32 + cl]      = f2bf(v0);
            C[(size_t)row * DEMB_ + col0 + wc * 32 + 16 + cl] = f2bf(v1);
        }
}

// ---------------- encoder GEMM, A=fp32 (converted during staging) ----------------
template<int K, bool RELU>
__global__ __launch_bounds__(512, 4) void egemm_f32a(
    const float* __restrict__ A, const unsigned short* __restrict__ Wt,
    const float* __restrict__ bias, unsigned short* __restrict__ C)
{
    __shared__ __align__(16) unsigned char Abuf[128 * 64 * 2];
    __shared__ __align__(16) unsigned char Bbuf[128 * 64 * 2];
    const int bid = blockIdx.x;
    const int row0 = (bid >> 2) * 128, col0 = (bid & 3) * 128;
    const int t = threadIdx.x;
    const int wave = t >> 6, lane = t & 63;
    const int wr = wave >> 2, wc = wave & 3;
    const int cl = lane & 15, rg = lane >> 4;

    const int pr0 = t >> 3, pq0 = t & 7;
    const int pr1 = pr0 + 64;
    const int ks0 = ((pq0 ^ (pr0 & 7)) * 8);   // B-side pre-swizzled source
    const int ks1 = ((pq0 ^ (pr1 & 7)) * 8);
    // A-side: swizzled LDS dest (reg staging)
    const int ad0 = pr0 * 128 + ((pq0 ^ (pr0 & 7)) << 4);
    const int ad1 = pr1 * 128 + ((pq0 ^ (pr1 & 7)) << 4);
    const float* Aglob = A + (size_t)row0 * K;
    const unsigned short* Bglob = Wt + (size_t)col0 * K;

    int aoff[4], asw[4], boff[2], bsw[2];
    #pragma unroll
    for (int m = 0; m < 4; ++m) {
        int r = wr * 64 + m * 16 + cl;
        aoff[m] = r * 128; asw[m] = (r & 7) << 4;
    }
    #pragma unroll
    for (int n = 0; n < 2; ++n) {
        int c = wc * 32 + n * 16 + cl;
        boff[n] = c * 128; bsw[n] = (c & 7) << 4;
    }

    f32x4 acc[4][2];
    #pragma unroll
    for (int m = 0; m < 4; ++m) {
        acc[m][0] = (f32x4){0.f, 0.f, 0.f, 0.f};
        acc[m][1] = (f32x4){0.f, 0.f, 0.f, 0.f};
    }
    for (int k0 = 0; k0 < K; k0 += 64) {
        gld_lds16(Bglob + (size_t)pr0 * K + k0 + ks0, Bbuf + t * 16);
        gld_lds16(Bglob + (size_t)pr1 * K + k0 + ks1, Bbuf + (t + 512) * 16);
        {
            const float* s0 = Aglob + (size_t)pr0 * K + k0 + pq0 * 8;
            const float* s1 = Aglob + (size_t)pr1 * K + k0 + pq0 * 8;
            float4 u0 = *(const float4*)(s0), u1 = *(const float4*)(s0 + 4);
            float4 u2 = *(const float4*)(s1), u3 = *(const float4*)(s1 + 4);
            ushort8 w0, w1;
            w0[0] = f2bf(u0.x); w0[1] = f2bf(u0.y); w0[2] = f2bf(u0.z); w0[3] = f2bf(u0.w);
            w0[4] = f2bf(u1.x); w0[5] = f2bf(u1.y); w0[6] = f2bf(u1.z); w0[7] = f2bf(u1.w);
            w1[0] = f2bf(u2.x); w1[1] = f2bf(u2.y); w1[2] = f2bf(u2.z); w1[3] = f2bf(u2.w);
            w1[4] = f2bf(u3.x); w1[5] = f2bf(u3.y); w1[6] = f2bf(u3.z); w1[7] = f2bf(u3.w);
            *(ushort8*)(Abuf + ad0) = w0;
            *(ushort8*)(Abuf + ad1) = w1;
        }
        __syncthreads();
        #pragma unroll
        for (int h = 0; h < 2; ++h) {
            const int cb = h * 64 + rg * 16;
            short8 av[4], bv[2];
            #pragma unroll
            for (int m = 0; m < 4; ++m)
                av[m] = *(const short8*)(Abuf + aoff[m] + (cb ^ asw[m]));
            #pragma unroll
            for (int n = 0; n < 2; ++n)
                bv[n] = *(const short8*)(Bbuf + boff[n] + (cb ^ bsw[n]));
            #pragma unroll
            for (int m = 0; m < 4; ++m)
                #pragma unroll
                for (int n = 0; n < 2; ++n)
                    acc[m][n] = __builtin_amdgcn_mfma_f32_16x16x32_bf16(
                        av[m], bv[n], acc[m][n], 0, 0, 0);
        }
        __syncthreads();
    }
    const float b0 = bias[col0 + wc * 32 + cl];
    const float b1 = bias[col0 + wc * 32 + 16 + cl];
    #pragma unroll
    for (int m = 0; m < 4; ++m)
        #pragma unroll
        for (int j = 0; j < 4; ++j) {
            int row = row0 + wr * 64 + m * 16 + rg * 4 + j;
            float v0 = acc[m][0][j] + b0;
            float v1 = acc[m][1][j] + b1;
            if (RELU) { v0 = fmaxf(v0, 0.f); v1 = fmaxf(v1, 0.f); }
            C[(size_t)row * DEMB_ + col0 + wc * 32 + cl]      = f2bf(v0);
            C[(size_t)row * DEMB_ + col0 + wc * 32 + 16 + cl] = f2bf(v1);
        }
}

// ---------------- LayerNorm (bf16 in/out), one wave per row ----------------
__global__ __launch_bounds__(256) void ln_bf16_kernel(
    unsigned short* __restrict__ h, const float* __restrict__ g, const float* __restrict__ b)
{
    const int lane = threadIdx.x & 63;
    const int row = blockIdx.x * 4 + (threadIdx.x >> 6);
    unsigned short* p = h + (size_t)row * DEMB_;
    ushort8 v = *(const ushort8*)(p + lane * 8);
    float x[8];
    #pragma unroll
    for (int i = 0; i < 8; ++i) x[i] = bf2f(v[i]);
    float s = 0.f;
    #pragma unroll
    for (int i = 0; i < 8; ++i) s += x[i];
    #pragma unroll
    for (int d = 32; d >= 1; d >>= 1) s += __shfl_xor(s, d);
    float mu = s * (1.f / DEMB_);
    float sq = 0.f;
    #pragma unroll
    for (int i = 0; i < 8; ++i) { float dd = x[i] - mu; sq += dd * dd; }
    #pragma unroll
    for (int d = 32; d >= 1; d >>= 1) sq += __shfl_xor(sq, d);
    float rs = 1.f / sqrtf(sq * (1.f / DEMB_) + LN_EPS_);
    float4 g0 = *(const float4*)(g + lane * 8);
    float4 g1 = *(const float4*)(g + lane * 8 + 4);
    float4 b0 = *(const float4*)(b + lane * 8);
    float4 b1 = *(const float4*)(b + lane * 8 + 4);
    float gg[8] = {g0.x, g0.y, g0.z, g0.w, g1.x, g1.y, g1.z, g1.w};
    float bb[8] = {b0.x, b0.y, b0.z, b0.w, b1.x, b1.y, b1.z, b1.w};
    ushort8 o;
    #pragma unroll
    for (int i = 0; i < 8; ++i) o[i] = f2bf((x[i] - mu) * rs * gg[i] + bb[i]);
    *(ushort8*)(p + lane * 8) = o;
}

// ---------------- L2 normalize rows (bf16 in -> bf16 out) ----------------
__global__ __launch_bounds__(256) void l2norm_bf16_kernel(
    const unsigned short* __restrict__ h, unsigned short* __restrict__ o)
{
    const int lane = threadIdx.x & 63;
    const int row = blockIdx.x * 4 + (threadIdx.x >> 6);
    const unsigned short* p = h + (size_t)row * DEMB_;
    ushort8 v = *(const ushort8*)(p + lane * 8);
    float x[8];
    #pragma unroll
    for (int i = 0; i < 8; ++i) x[i] = bf2f(v[i]);
    float sq = 0.f;
    #pragma unroll
    for (int i = 0; i < 8; ++i) sq += x[i] * x[i];
    #pragma unroll
    for (int d = 32; d >= 1; d >>= 1) sq += __shfl_xor(sq, d);
    float rs = 1.f / sqrtf(sq);
    ushort8 w;
    #pragma unroll
    for (int i = 0; i < 8; ++i) w[i] = f2bf(x[i] * rs);
    *(ushort8*)(o + (size_t)row * DEMB_ + lane * 8) = w;
}

// ---------------- Fused sim (bf16 MFMA) + masked max + masked mean ----------------
__global__ __launch_bounds__(512, 4) void sim_mfma_kernel(
    const unsigned short* __restrict__ hA,  // bf16 [32*128, 512]
    const unsigned short* __restrict__ hB,  // bf16 [32*1024, 512]
    const int* __restrict__ mA, const int* __restrict__ mB,
    const float* __restrict__ temp, float* __restrict__ out)
{
    __shared__ __align__(16) unsigned char Abuf[128 * 64 * 2];
    __shared__ __align__(16) unsigned char Bbuf[128 * 64 * 2];
    __shared__ float rowpart[4][128];
    __shared__ float colpart[2][128];
    __shared__ float red[2][4];

    const int bid = blockIdx.x;
    const int g = (bid & 7) * 128 + (bid >> 3);
    const int b = g >> 5, a = g & 31;

    const int t = threadIdx.x;
    const int wave = t >> 6, lane = t & 63;
    const int wr = wave >> 2, wc = wave & 3;
    const int cl = lane & 15, rg = lane >> 4;
    const float invT = 1.0f / temp[0];

    const int pr0 = t >> 3, pq0 = t & 7;
    const int pr1 = pr0 + 64;
    const int ks0 = ((pq0 ^ (pr0 & 7)) * 8);
    const int ks1 = ((pq0 ^ (pr1 & 7)) * 8);
    const unsigned short* Aglob = hA + (size_t)(a * TA_) * DEMB_;
    const unsigned short* Bglob = hB + (size_t)(b * TB_) * DEMB_;

    unsigned mabits = 0;
    #pragma unroll
    for (int m = 0; m < 4; ++m)
        #pragma unroll
        for (int j = 0; j < 4; ++j) {
            int r = wr * 64 + m * 16 + rg * 4 + j;
            if (mA[a * TA_ + r]) mabits |= 1u << (m * 4 + j);
        }

    int aoff[4], asw[4], boff[2], bsw[2];
    #pragma unroll
    for (int m = 0; m < 4; ++m) {
        int r = wr * 64 + m * 16 + cl;
        aoff[m] = r * 128; asw[m] = (r & 7) << 4;
    }
    #pragma unroll
    for (int n = 0; n < 2; ++n) {
        int c = wc * 32 + n * 16 + cl;
        boff[n] = c * 128; bsw[n] = (c & 7) << 4;
    }

    float rowrun = -FLT_MAX, sumB = 0.f, cntB = 0.f;

    for (int s0 = 0; s0 < TB_; s0 += 128) {
        const int mb0 = mB[b * TB_ + s0 + wc * 32 + cl];
        const int mb1 = mB[b * TB_ + s0 + wc * 32 + 16 + cl];
        f32x4 acc[4][2];
        #pragma unroll
        for (int m = 0; m < 4; ++m) {
            acc[m][0] = (f32x4){0.f, 0.f, 0.f, 0.f};
            acc[m][1] = (f32x4){0.f, 0.f, 0.f, 0.f};
        }
        for (int k0 = 0; k0 < DEMB_; k0 += 64) {
            gld_lds16(Aglob + (size_t)pr0 * DEMB_ + k0 + ks0, Abuf + t * 16);
            gld_lds16(Aglob + (size_t)pr1 * DEMB_ + k0 + ks1, Abuf + (t + 512) * 16);
            gld_lds16(Bglob + (size_t)(s0 + pr0) * DEMB_ + k0 + ks0, Bbuf + t * 16);
            gld_lds16(Bglob + (size_t)(s0 + pr1) * DEMB_ + k0 + ks1, Bbuf + (t + 512) * 16);
            __syncthreads();
            #pragma unroll
            for (int h = 0; h < 2; ++h) {
                const int cb = h * 64 + rg * 16;
                short8 av[4], bv[2];
                #pragma unroll
                for (int m = 0; m < 4; ++m)
                    av[m] = *(const short8*)(Abuf + aoff[m] + (cb ^ asw[m]));
                #pragma unroll
                for (int n = 0; n < 2; ++n)
                    bv[n] = *(const short8*)(Bbuf + boff[n] + (cb ^ bsw[n]));
                #pragma unroll
                for (int m = 0; m < 4; ++m)
                    #pragma unroll
                    for (int n = 0; n < 2; ++n)
                        acc[m][n] = __builtin_amdgcn_mfma_f32_16x16x32_bf16(
                            av[m], bv[n], acc[m][n], 0, 0, 0);
            }
            __syncthreads();
        }
        float rmax[4][4];
        float cmax0 = -FLT_MAX, cmax1 = -FLT_MAX;
        #pragma unroll
        for (int m = 0; m < 4; ++m) {
            #pragma unroll
            for (int j = 0; j < 4; ++j) {
                const bool ra = (mabits >> (m * 4 + j)) & 1;
                float v0 = (ra && mb0) ? acc[m][0][j] * invT : -FLT_MAX;
                float v1 = (ra && mb1) ? acc[m][1][j] * invT : -FLT_MAX;
                rmax[m][j] = fmaxf(v0, v1);
                cmax0 = fmaxf(cmax0, v0);
                cmax1 = fmaxf(cmax1, v1);
            }
        }
        #pragma unroll
        for (int d = 1; d < 16; d <<= 1)
            #pragma unroll
            for (int m = 0; m < 4; ++m)
                #pragma unroll
                for (int j = 0; j < 4; ++j)
                    rmax[m][j] = fmaxf(rmax[m][j], __shfl_xor(rmax[m][j], d));
        cmax0 = fmaxf(cmax0, __shfl_xor(cmax0, 16));
        cmax0 = fmaxf(cmax0, __shfl_xor(cmax0, 32));
        cmax1 = fmaxf(cmax1, __shfl_xor(cmax1, 16));
        cmax1 = fmaxf(cmax1, __shfl_xor(cmax1, 32));
        if (cl == 0) {
            #pragma unroll
            for (int m = 0; m < 4; ++m)
                #pragma unroll
                for (int j = 0; j < 4; ++j)
                    rowpart[wc][wr * 64 + m * 16 + rg * 4 + j] = rmax[m][j];
        }
        if (rg == 0) {
            colpart[wr][wc * 32 + cl]      = cmax0;
            colpart[wr][wc * 32 + 16 + cl] = cmax1;
        }
        __syncthreads();
        if (t < 128) {
            float r = fmaxf(fmaxf(rowpart[0][t], rowpart[1][t]),
                            fmaxf(rowpart[2][t], rowpart[3][t]));
            rowrun = fmaxf(rowrun, r);
            float cm = fmaxf(colpart[0][t], colpart[1][t]);
            if (mB[b * TB_ + s0 + t]) { sumB += cm; cntB += 1.f; }
        }
        __syncthreads();
    }

    float numA = 0.f, cA = 0.f;
    if (t < 128 && mA[a * TA_ + t]) { numA = rowrun; cA = 1.f; }
    #pragma unroll
    for (int d = 32; d >= 1; d >>= 1) {
        numA += __shfl_xor(numA, d);
        cA   += __shfl_xor(cA, d);
        sumB += __shfl_xor(sumB, d);
        cntB += __shfl_xor(cntB, d);
    }
    if (wave < 2 && lane == 0) {
        red[wave][0] = numA; red[wave][1] = cA;
        red[wave][2] = sumB; red[wave][3] = cntB;
    }
    __syncthreads();
    if (t == 0) {
        float n  = red[0][0] + red[1][0];
        float c  = red[0][1] + red[1][1];
        float nb = red[0][2] + red[1][2];
        float cb = red[0][3] + red[1][3];
        out[a * NBAT_ + b] = n / fmaxf(c, 1e-6f);
        out[NBAT_ * NBAT_ + a * NBAT_ + b] = nb / fmaxf(cb, 1e-6f);
    }
}

// ---------------- launch ----------------
extern "C" void kernel_launch(void* const* d_in, const int* in_sizes, int n_in,
                              void* d_out, int out_size, void* d_ws, size_t ws_size,
                              hipStream_t stream)
{
    const float* pep_esm  = (const float*)d_in[0];
    const float* rec_esm  = (const float*)d_in[1];
    const int*   pep_mask = (const int*)d_in[2];
    const int*   rec_mask = (const int*)d_in[3];
    const float* temp     = (const float*)d_in[4];
    const float* pep_pw  = (const float*)d_in[5];
    const float* pep_pb  = (const float*)d_in[6];
    const float* pep_f1w = (const float*)d_in[7];
    const float* pep_f1b = (const float*)d_in[8];
    const float* pep_lng = (const float*)d_in[9];
    const float* pep_lnb = (const float*)d_in[10];
    const float* pep_f2w = (const float*)d_in[11];
    const float* pep_f2b = (const float*)d_in[12];
    const float* rec_pw  = (const float*)d_in[13];
    const float* rec_pb  = (const float*)d_in[14];
    const float* rec_f1w = (const float*)d_in[15];
    const float* rec_f1b = (const float*)d_in[16];
    const float* rec_lng = (const float*)d_in[17];
    const float* rec_lnb = (const float*)d_in[18];
    const float* rec_f2w = (const float*)d_in[19];
    const float* rec_f2b = (const float*)d_in[20];
    float* out = (float*)d_out;

    const int Mr = NBAT_ * TB_;   // 32768
    const int Mp = NBAT_ * TA_;   // 4096

    // workspace layout (bytes)
    char* base = (char*)d_ws;
    unsigned short* R1    = (unsigned short*)(base);                           // 32MB
    unsigned short* R2    = (unsigned short*)(base + ((size_t)32 << 20));      // 32MB
    unsigned short* hB_bf = (unsigned short*)(base + ((size_t)64 << 20));      // 32MB
    unsigned short* hA_bf = (unsigned short*)(base + ((size_t)96 << 20));      // 4MB
    unsigned short* wts   = (unsigned short*)(base + ((size_t)101 << 20));     // ~4.6MB weights
    unsigned short* rec_pwt  = wts;                    // 512x1280
    unsigned short* pep_pwt  = rec_pwt + 512 * 1280;
    unsigned short* rec_f1wt = pep_pwt + 512 * 1280;   // 512x512
    unsigned short* rec_f2wt = rec_f1wt + 512 * 512;
    unsigned short* pep_f1wt = rec_f2wt + 512 * 512;
    unsigned short* pep_f2wt = pep_f1wt + 512 * 512;

    dim3 b256(256);
    // weight transpose+convert
    wtrans_kernel<<<dim3(DIN_ / 32, DEMB_ / 32), b256, 0, stream>>>(rec_pw, rec_pwt, DIN_, DEMB_);
    wtrans_kernel<<<dim3(DIN_ / 32, DEMB_ / 32), b256, 0, stream>>>(pep_pw, pep_pwt, DIN_, DEMB_);
    wtrans_kernel<<<dim3(DEMB_ / 32, DEMB_ / 32), b256, 0, stream>>>(rec_f1w, rec_f1wt, DEMB_, DEMB_);
    wtrans_kernel<<<dim3(DEMB_ / 32, DEMB_ / 32), b256, 0, stream>>>(rec_f2w, rec_f2wt, DEMB_, DEMB_);
    wtrans_kernel<<<dim3(DEMB_ / 32, DEMB_ / 32), b256, 0, stream>>>(pep_f1w, pep_f1wt, DEMB_, DEMB_);
    wtrans_kernel<<<dim3(DEMB_ / 32, DEMB_ / 32), b256, 0, stream>>>(pep_f2w, pep_f2wt, DEMB_, DEMB_);

    // --- rec encoder (bf16 MFMA) ---
    egemm_f32a<DIN_, false><<<dim3((Mr / 128) * 4), dim3(512), 0, stream>>>(rec_esm, rec_pwt, rec_pb, R1);
    egemm_bf16<DEMB_, true><<<dim3((Mr / 128) * 4), dim3(512), 0, stream>>>(R1, rec_f1wt, rec_f1b, R2);
    ln_bf16_kernel<<<dim3(Mr / 4), b256, 0, stream>>>(R2, rec_lng, rec_lnb);
    egemm_bf16<DEMB_, false><<<dim3((Mr / 128) * 4), dim3(512), 0, stream>>>(R2, rec_f2wt, rec_f2b, R1);
    l2norm_bf16_kernel<<<dim3(Mr / 4), b256, 0, stream>>>(R1, hB_bf);
    // --- pep encoder ---
    egemm_f32a<DIN_, false><<<dim3((Mp / 128) * 4), dim3(512), 0, stream>>>(pep_esm, pep_pwt, pep_pb, R1);
    egemm_bf16<DEMB_, true><<<dim3((Mp / 128) * 4), dim3(512), 0, stream>>>(R1, pep_f1wt, pep_f1b, R2);
    ln_bf16_kernel<<<dim3(Mp / 4), b256, 0, stream>>>(R2, pep_lng, pep_lnb);
    egemm_bf16<DEMB_, false><<<dim3((Mp / 128) * 4), dim3(512), 0, stream>>>(R2, pep_f2wt, pep_f2b, R1);
    l2norm_bf16_kernel<<<dim3(Mp / 4), b256, 0, stream>>>(R1, hA_bf);
    // --- fused similarity (bf16 MFMA) ---
    sim_mfma_kernel<<<dim3(NBAT_ * NBAT_), dim3(512), 0, stream>>>(hA_bf, hB_bf, pep_mask, rec_mask, temp, out);
}